// Round 13
// baseline (5409.829 us; speedup 1.0000x reference)
//
#include <hip/hip_runtime.h>
#include <cstddef>

namespace {

constexpr int B  = 128;
constexpr int T  = 256;
constexpr int HD = 512;
constexpr int G  = 2048;   // 4*HD gates
constexpr int TC = 16;     // time chunk for xg buffer (double-buffered)
constexpr int XIN = 36;    // 32 real + 4 cat
constexpr int NCHUNK = T / TC;   // 16

typedef __attribute__((ext_vector_type(8))) short short8;
typedef __attribute__((ext_vector_type(4))) short short4v;
typedef __attribute__((ext_vector_type(4))) float f32x4;

union U16B { uint4 u; short8 s; };

__device__ __forceinline__ float sigmf(float x) { return 1.0f / (1.0f + expf(-x)); }
__device__ __forceinline__ float leakyf(float x) { return x >= 0.0f ? x : 0.1f * x; }

__device__ __forceinline__ unsigned short f2bf(float v) {
  union { float f; unsigned u; } x; x.f = v;
  unsigned r = x.u + 0x7fffu + ((x.u >> 16) & 1u);
  return (unsigned short)(r >> 16);
}
__device__ __forceinline__ float bf2f(unsigned short b) {
  union { unsigned u; float f; } x; x.u = ((unsigned)b) << 16; return x.f;
}

// ---------------- prep: transpose [K][N] -> [N][K], split bf16 hi/lo ----------------
__global__ void k_prep(const float* __restrict__ src, unsigned short* __restrict__ dh,
                       unsigned short* __restrict__ dl, int K, int N) {
  __shared__ float tile[32][33];
  const int n0 = blockIdx.x * 32, k0 = blockIdx.y * 32;
  for (int i = threadIdx.y; i < 32; i += 8)
    tile[i][threadIdx.x] = src[(size_t)(k0 + i) * N + n0 + threadIdx.x];
  __syncthreads();
  for (int i = threadIdx.y; i < 32; i += 8) {
    const float v = tile[threadIdx.x][i];
    const unsigned short h = f2bf(v);
    const size_t o = (size_t)(n0 + i) * K + k0 + threadIdx.x;
    dh[o] = h;
    dl[o] = f2bf(v - bf2f(h));
  }
}

// ---------------- prep+pack Wh directly into MFMA A-fragment order ----------------
__global__ void k_prep_pack(const float* __restrict__ Whf, const float* __restrict__ Whr,
                            unsigned short* __restrict__ wpkh, unsigned short* __restrict__ wpkl) {
  const int f = blockIdx.x * 256 + threadIdx.x;   // 262144
  const int l  = f & 63;
  const int ks = (f >> 6) & 15;
  const int ct = (f >> 10) & 7;
  const int ut = (f >> 13) & 15;
  const int dir = f >> 17;
  const float* src = dir ? Whr : Whf;
  const int L = ct * 16 + (l & 15);
  const int gcol = (L >> 5) * HD + ut * 32 + (L & 31);
  const int k0 = ks * 32 + (l >> 4) * 8;
  short8 hv, lv;
  #pragma unroll
  for (int j = 0; j < 8; ++j) {
    const float v = src[(size_t)(k0 + j) * G + gcol];
    const unsigned short h = f2bf(v);
    hv[j] = (short)h;
    lv[j] = (short)f2bf(v - bf2f(h));
  }
  *(short8*)&wpkh[(size_t)f * 8] = hv;
  *(short8*)&wpkl[(size_t)f * 8] = lv;
}

__global__ void k_bias(const float* __restrict__ bif, const float* __restrict__ bhf,
                       const float* __restrict__ bir, const float* __restrict__ bhr,
                       float* __restrict__ biasI) {
  const int i = blockIdx.x * 256 + threadIdx.x;   // 4096
  const int d = i >> 11, n = i & 2047;
  biasI[i] = (d ? bir[n] : bif[n]) + (d ? bhr[n] : bhf[n]);
}

// ---------------- K1: embed-gather + GEMM (M=B*T, K=64, N=512) + leaky, out bf16 hi/lo ----------
__global__ void k_embed_gemm1(const float* __restrict__ x0, const float* __restrict__ emb,
                              const float* __restrict__ W1, const float* __restrict__ b1,
                              unsigned short* __restrict__ x1h, unsigned short* __restrict__ x1l) {
  __shared__ float As[64][65];
  __shared__ float Bs[64][68];
  const int tid = threadIdx.x;
  const int m0 = blockIdx.x * 64, n0 = blockIdx.y * 64;

  for (int i = tid; i < 64 * 64; i += 256) {
    const int m = i >> 6, k = i & 63;
    const size_t row = (size_t)(m0 + m);
    float v;
    if (k < 32) {
      v = x0[row * XIN + k];
    } else {
      const int c = (k - 32) >> 3, e = (k - 32) & 7;
      const int idx = (int)x0[row * XIN + 32 + c];
      v = emb[(size_t)(c * 100 + idx) * 8 + e];
    }
    As[m][k] = v;
  }
  for (int j = 0; j < 4; ++j) {
    const int q = tid + 256 * j;
    const int kk = q >> 4, nq = q & 15;
    *(float4*)&Bs[kk][nq * 4] = *(const float4*)&W1[(size_t)kk * HD + n0 + nq * 4];
  }
  __syncthreads();

  const int ty = tid >> 4, tx = tid & 15;
  float acc[4][4] = {};
  #pragma unroll 8
  for (int k = 0; k < 64; ++k) {
    const float a0 = As[ty * 4 + 0][k], a1 = As[ty * 4 + 1][k];
    const float a2 = As[ty * 4 + 2][k], a3 = As[ty * 4 + 3][k];
    const float4 bv = *(const float4*)&Bs[k][tx * 4];
    acc[0][0] += a0 * bv.x; acc[0][1] += a0 * bv.y; acc[0][2] += a0 * bv.z; acc[0][3] += a0 * bv.w;
    acc[1][0] += a1 * bv.x; acc[1][1] += a1 * bv.y; acc[1][2] += a1 * bv.z; acc[1][3] += a1 * bv.w;
    acc[2][0] += a2 * bv.x; acc[2][1] += a2 * bv.y; acc[2][2] += a2 * bv.z; acc[2][3] += a2 * bv.w;
    acc[3][0] += a3 * bv.x; acc[3][1] += a3 * bv.y; acc[3][2] += a3 * bv.z; acc[3][3] += a3 * bv.w;
  }
  const float4 b4 = *(const float4*)&b1[n0 + tx * 4];
  for (int i = 0; i < 4; ++i) {
    float o[4];
    o[0] = leakyf(acc[i][0] + b4.x);
    o[1] = leakyf(acc[i][1] + b4.y);
    o[2] = leakyf(acc[i][2] + b4.z);
    o[3] = leakyf(acc[i][3] + b4.w);
    short4v hv, lv;
    #pragma unroll
    for (int p = 0; p < 4; ++p) {
      const unsigned short hb = f2bf(o[p]);
      hv[p] = (short)hb;
      lv[p] = (short)f2bf(o[p] - bf2f(hb));
    }
    const size_t off = (size_t)(m0 + ty * 4 + i) * HD + n0 + tx * 4;
    *(short4v*)&x1h[off] = hv;
    *(short4v*)&x1l[off] = lv;
  }
}

// ---------------- K2/K3: bf16x3 MFMA GEMM, tile 128x128, BK=32 (standalone) ----------------
template <int MODE>
__global__ __launch_bounds__(512) void k_mm(
    const unsigned short* __restrict__ Ah, const unsigned short* __restrict__ Al,
    const unsigned short* __restrict__ Bh, const unsigned short* __restrict__ Bl,
    const float* __restrict__ bias,
    unsigned short* __restrict__ oh, unsigned short* __restrict__ ol,
    float* __restrict__ of, int c0) {
  __shared__ unsigned short As_h[128 * 40], As_l[128 * 40];
  __shared__ unsigned short Bs_h[128 * 40], Bs_l[128 * 40];
  const int tid = threadIdx.x;
  const int m0 = blockIdx.x * 128, n0 = blockIdx.y * 128;
  const int dir = MODE ? (m0 / (TC * B)) : 0;
  const unsigned short* Bhd = Bh + (size_t)dir * G * HD;
  const unsigned short* Bld = Bl + (size_t)dir * G * HD;

  const int si = tid >> 2, sseg = tid & 3;
  int arow;
  if (MODE) {
    const int r = m0 + si;
    const int tc = (r >> 7) & (TC - 1), bb = r & (B - 1);
    const int tg = dir ? (T - 1 - (c0 + tc)) : (c0 + tc);
    arow = bb * T + tg;
  } else {
    arow = m0 + si;
  }
  const int brow = n0 + si;

  const int lane = tid & 63;
  const int c16 = lane & 15, q = lane >> 4;
  const int w = tid >> 6;
  const int mg = w & 3, ng = w >> 2;

  f32x4 acc[2][4] = {};

  for (int k0 = 0; k0 < HD; k0 += 32) {
    __syncthreads();
    *(short8*)&As_h[si * 40 + sseg * 8] = *(const short8*)&Ah[(size_t)arow * HD + k0 + sseg * 8];
    *(short8*)&As_l[si * 40 + sseg * 8] = *(const short8*)&Al[(size_t)arow * HD + k0 + sseg * 8];
    *(short8*)&Bs_h[si * 40 + sseg * 8] = *(const short8*)&Bhd[(size_t)brow * HD + k0 + sseg * 8];
    *(short8*)&Bs_l[si * 40 + sseg * 8] = *(const short8*)&Bld[(size_t)brow * HD + k0 + sseg * 8];
    __syncthreads();

    short8 ah[2], al[2], bh[4], bl[4];
    #pragma unroll
    for (int a = 0; a < 2; ++a) {
      const int rr = (2 * mg + a) * 16 + c16;
      ah[a] = *(const short8*)&As_h[rr * 40 + q * 8];
      al[a] = *(const short8*)&As_l[rr * 40 + q * 8];
    }
    #pragma unroll
    for (int j = 0; j < 4; ++j) {
      const int rr = (4 * ng + j) * 16 + c16;
      bh[j] = *(const short8*)&Bs_h[rr * 40 + q * 8];
      bl[j] = *(const short8*)&Bs_l[rr * 40 + q * 8];
    }
    #pragma unroll
    for (int a = 0; a < 2; ++a)
      #pragma unroll
      for (int j = 0; j < 4; ++j) {
        acc[a][j] = __builtin_amdgcn_mfma_f32_16x16x32_bf16(ah[a], bh[j], acc[a][j], 0, 0, 0);
        acc[a][j] = __builtin_amdgcn_mfma_f32_16x16x32_bf16(ah[a], bl[j], acc[a][j], 0, 0, 0);
        acc[a][j] = __builtin_amdgcn_mfma_f32_16x16x32_bf16(al[a], bh[j], acc[a][j], 0, 0, 0);
      }
  }

  #pragma unroll
  for (int a = 0; a < 2; ++a) {
    #pragma unroll
    for (int j = 0; j < 4; ++j) {
      const int nn = n0 + (4 * ng + j) * 16 + c16;
      const float bv = MODE ? bias[dir * G + nn] : bias[nn];
      #pragma unroll
      for (int r = 0; r < 4; ++r) {
        const int mm = m0 + (2 * mg + a) * 16 + 4 * q + r;
        float v = acc[a][j][r] + bv;
        if (MODE) {
          of[(size_t)mm * G + nn] = v;
        } else {
          v = leakyf(v);
          const unsigned short hb = f2bf(v);
          oh[(size_t)mm * HD + nn] = hb;
          ol[(size_t)mm * HD + nn] = f2bf(v - bf2f(hb));
        }
      }
    }
  }
}

// ---------------- K4: fused per-chunk kernel — wave-specialized scan + shadow xg GEMM --------
// 256 blocks x 1024 thr (cooperative, 1 block/CU: 16 waves, launch_bounds(1024,4) caps VGPR
// at 128 so coop admissibility is guaranteed). Waves 0-7 (half==0): the round-12 scan protocol
// verbatim (identity block decode, coalesced u32 staging, perm-in-KSTEP, absolute-t flags).
// Waves 8-15 (half==1): next chunk's xg GEMM, 2 tiles/block x 16 BK=32 slices, advanced
// 2 slices per scan step in the barrier slots' shadow. EXACTLY 5 __syncthreads per tc on
// every path (t==0/tc==0 branches padded) — halves cannot mismatch.
__global__ __launch_bounds__(1024, 4) void k_scan2(
    const float* __restrict__ xg, float* __restrict__ xgn,
    const unsigned short* __restrict__ wpkh, const unsigned short* __restrict__ wpkl,
    unsigned int* __restrict__ hpk, float* __restrict__ cbuf,
    float* __restrict__ part, const float* __restrict__ W3,
    int* __restrict__ flags, int c0,
    const unsigned short* __restrict__ x2h, const unsigned short* __restrict__ x2l,
    const unsigned short* __restrict__ wih, const unsigned short* __restrict__ wil,
    const float* __restrict__ bia, int dog) {
  __shared__ unsigned int hst[16 * 516];   // scan: staged packed h(t-1) [b][k]
  __shared__ float gl[128 * 17];           // scan: gates [L][b]
  __shared__ float ysum[16 * 33];          // scan: y partials
  __shared__ unsigned short gAh[128 * 40], gAl[128 * 40];   // gemm staging
  __shared__ unsigned short gBh[128 * 40], gBl[128 * 40];

  const int tid  = threadIdx.x;
  const int half = tid >> 9;       // 0 = scan waves, 1 = gemm waves
  const int stid = tid & 511;
  const int bid  = blockIdx.x;

  // ---- scan decode (identity: bid%8 = bt keeps each h-exchange group on one XCD) ----
  const int dir = bid >> 7;
  const int ut  = (bid >> 3) & 15;
  const int bt  = bid & 7;
  const int u0 = ut * 32, b0 = bt * 16;
  const int w = stid >> 6, lane = stid & 63;
  const int r16 = lane & 15, q = lane >> 4;
  const unsigned short* wp = wpkh + ((size_t)(((dir * 16 + ut) * 8 + w) * 16) << 9) + lane * 8;
  const unsigned short* wq = wpkl + ((size_t)(((dir * 16 + ut) * 8 + w) * 16) << 9) + lane * 8;

  const int b_l = stid >> 5, u2 = stid & 31;
  const int bg = b0 + b_l, jg = u0 + u2;
  const size_t ci = ((size_t)dir * B + bg) * HD + jg;
  float creg = 0.0f;
  if (half == 0 && c0 > 0) creg = cbuf[ci];
  const float w3v = W3[dir * HD + jg];
  const int fl_base = dir * 8 + bt;
  const int hb = r16 * 516 + q * 8;

  // ---- gemm decode ----
  const int gsi = stid >> 2, gseg = stid & 3;
  const int gw = stid >> 6, glane = stid & 63;
  const int gc16 = glane & 15, gq = glane >> 4;
  const int gmg = gw & 3, gng = gw >> 2;
  const int c0n = c0 + TC;
  f32x4 gacc[2][4] = {};

#define GEMM_STAGE(g) { \
    const int tt = bid * 2 + ((g) >> 4); const int ls = (g) & 15; \
    const int m0g = (tt & 31) * 128, n0g = (tt >> 5) * 128; \
    const int dirg = m0g >> 11; \
    const int rr0 = m0g + gsi; \
    const int tcc = (rr0 >> 7) & (TC - 1), bb2 = rr0 & (B - 1); \
    const int tg = dirg ? (T - 1 - (c0n + tcc)) : (c0n + tcc); \
    const int arow = bb2 * T + tg; \
    const int brow = n0g + gsi; \
    const int k0g = ls * 32; \
    const unsigned short* Bh2 = wih + (size_t)dirg * G * HD; \
    const unsigned short* Bl2 = wil + (size_t)dirg * G * HD; \
    *(short8*)&gAh[gsi * 40 + gseg * 8] = *(const short8*)&x2h[(size_t)arow * HD + k0g + gseg * 8]; \
    *(short8*)&gAl[gsi * 40 + gseg * 8] = *(const short8*)&x2l[(size_t)arow * HD + k0g + gseg * 8]; \
    *(short8*)&gBh[gsi * 40 + gseg * 8] = *(const short8*)&Bh2[(size_t)brow * HD + k0g + gseg * 8]; \
    *(short8*)&gBl[gsi * 40 + gseg * 8] = *(const short8*)&Bl2[(size_t)brow * HD + k0g + gseg * 8]; }

#define GEMM_MFMA(g) { \
    const int ls = (g) & 15; \
    if (ls == 0) { \
      _Pragma("unroll") for (int a = 0; a < 2; ++a) \
        _Pragma("unroll") for (int j = 0; j < 4; ++j) \
          gacc[a][j] = (f32x4){0.f, 0.f, 0.f, 0.f}; \
    } \
    short8 ah[2], al[2], bh4[4], bl4[4]; \
    _Pragma("unroll") for (int a = 0; a < 2; ++a) { \
      const int rr = (2 * gmg + a) * 16 + gc16; \
      ah[a] = *(const short8*)&gAh[rr * 40 + gq * 8]; \
      al[a] = *(const short8*)&gAl[rr * 40 + gq * 8]; \
    } \
    _Pragma("unroll") for (int j = 0; j < 4; ++j) { \
      const int rr = (4 * gng + j) * 16 + gc16; \
      bh4[j] = *(const short8*)&gBh[rr * 40 + gq * 8]; \
      bl4[j] = *(const short8*)&gBl[rr * 40 + gq * 8]; \
    } \
    _Pragma("unroll") for (int a = 0; a < 2; ++a) \
      _Pragma("unroll") for (int j = 0; j < 4; ++j) { \
        gacc[a][j] = __builtin_amdgcn_mfma_f32_16x16x32_bf16(ah[a], bh4[j], gacc[a][j], 0, 0, 0); \
        gacc[a][j] = __builtin_amdgcn_mfma_f32_16x16x32_bf16(ah[a], bl4[j], gacc[a][j], 0, 0, 0); \
        gacc[a][j] = __builtin_amdgcn_mfma_f32_16x16x32_bf16(al[a], bh4[j], gacc[a][j], 0, 0, 0); \
      } \
    if (ls == 15) { \
      const int tt = bid * 2 + ((g) >> 4); \
      const int m0g = (tt & 31) * 128, n0g = (tt >> 5) * 128; \
      const int dirg = m0g >> 11; \
      _Pragma("unroll") for (int a = 0; a < 2; ++a) \
        _Pragma("unroll") for (int j = 0; j < 4; ++j) { \
          const int nn = n0g + (4 * gng + j) * 16 + gc16; \
          const float bv = bia[dirg * G + nn]; \
          _Pragma("unroll") for (int r = 0; r < 4; ++r) { \
            const int mm = m0g + (2 * gmg + a) * 16 + 4 * gq + r; \
            xgn[(size_t)mm * G + nn] = gacc[a][j][r] + bv; \
          } \
        } \
    } }

#define KSTEP(K) { \
    const short8 whv = *(const short8*)(wp + (K) * 512); \
    const short8 wlv = *(const short8*)(wq + (K) * 512); \
    const uint4 aa = *(const uint4*)&hst[hb + (K) * 32]; \
    const uint4 bb = *(const uint4*)&hst[hb + (K) * 32 + 4]; \
    U16B hiu, lou; \
    hiu.u.x = __builtin_amdgcn_perm(aa.y, aa.x, 0x07060302u); \
    hiu.u.y = __builtin_amdgcn_perm(aa.w, aa.z, 0x07060302u); \
    hiu.u.z = __builtin_amdgcn_perm(bb.y, bb.x, 0x07060302u); \
    hiu.u.w = __builtin_amdgcn_perm(bb.w, bb.z, 0x07060302u); \
    lou.u.x = __builtin_amdgcn_perm(aa.y, aa.x, 0x05040100u); \
    lou.u.y = __builtin_amdgcn_perm(aa.w, aa.z, 0x05040100u); \
    lou.u.z = __builtin_amdgcn_perm(bb.y, bb.x, 0x05040100u); \
    lou.u.w = __builtin_amdgcn_perm(bb.w, bb.z, 0x05040100u); \
    acc = __builtin_amdgcn_mfma_f32_16x16x32_bf16(whv, hiu.s, acc, 0, 0, 0); \
    acc = __builtin_amdgcn_mfma_f32_16x16x32_bf16(whv, lou.s, acc, 0, 0, 0); \
    acc = __builtin_amdgcn_mfma_f32_16x16x32_bf16(wlv, hiu.s, acc, 0, 0, 0); }

  for (int tc = 0; tc < TC; ++tc) {
    const int t = c0 + tc;
    float xgf = 0.f, xgi = 0.f, xga = 0.f, xgo = 0.f;
    f32x4 acc = {0.0f, 0.0f, 0.0f, 0.0f};

    // slot 0 (pre-B1): scan prefetch + spin  |  gemm stage slice 2tc
    if (half == 0) {
      const float* xr = xg + (((size_t)dir * TC + tc) * B + bg) * G;
      xgf = xr[jg];
      xgi = xr[HD + jg];
      xga = xr[2 * HD + jg];
      xgo = xr[3 * HD + jg];
      if (tc > 0 && stid == 0) {
        while (__hip_atomic_load(&flags[(t - 1) * 16 + fl_base], __ATOMIC_RELAXED,
                                 __HIP_MEMORY_SCOPE_AGENT) < 16)
          __builtin_amdgcn_s_sleep(1);
      }
    } else if (dog) {
      GEMM_STAGE(2 * tc)
    }
    __syncthreads();   // B1

    // slot 1: scan stage h  |  gemm mfma slice 2tc
    if (half == 0) {
      if (t > 0) {
        const unsigned int* hsrc = hpk + ((size_t)((t & 1) * 2 + dir) * B + b0) * HD;
        unsigned int hv[16];
        #pragma unroll
        for (int i = 0; i < 16; ++i)
          hv[i] = __hip_atomic_load(&hsrc[i * HD + stid], __ATOMIC_RELAXED,
                                    __HIP_MEMORY_SCOPE_AGENT);
        #pragma unroll
        for (int i = 0; i < 16; ++i)
          hst[i * 516 + stid] = hv[i];
      }
    } else if (dog) {
      GEMM_MFMA(2 * tc)
    }
    __syncthreads();   // B2

    // slot 2: scan KSTEP  |  gemm stage slice 2tc+1
    if (half == 0) {
      if (t > 0) {
        KSTEP(0) KSTEP(1) KSTEP(2) KSTEP(3) KSTEP(4) KSTEP(5) KSTEP(6) KSTEP(7)
        KSTEP(8) KSTEP(9) KSTEP(10) KSTEP(11) KSTEP(12) KSTEP(13) KSTEP(14) KSTEP(15)
      }
    } else if (dog) {
      GEMM_STAGE(2 * tc + 1)
    }
    __syncthreads();   // B3

    // slot 3: scan scatter  |  gemm mfma slice 2tc+1
    if (half == 0) {
      gl[(w * 16 + q * 4 + 0) * 17 + r16] = acc[0];
      gl[(w * 16 + q * 4 + 1) * 17 + r16] = acc[1];
      gl[(w * 16 + q * 4 + 2) * 17 + r16] = acc[2];
      gl[(w * 16 + q * 4 + 3) * 17 + r16] = acc[3];
    } else if (dog) {
      GEMM_MFMA(2 * tc + 1)
    }
    __syncthreads();   // B4

    // slot 4: scan epilogue  |  gemm idle
    if (half == 0) {
      const float gf = gl[(u2) * 17 + b_l]      + xgf;
      const float gi = gl[(32 + u2) * 17 + b_l] + xgi;
      const float ga = gl[(64 + u2) * 17 + b_l] + xga;
      const float go = gl[(96 + u2) * 17 + b_l] + xgo;
      const float cn = sigmf(gf) * creg + sigmf(gi) * tanhf(ga);
      const float hn = sigmf(go) * tanhf(cn);
      creg = cn;
      const unsigned short hh = f2bf(hn);
      const unsigned int hp = ((unsigned)hh << 16) | (unsigned)f2bf(hn - bf2f(hh));
      __hip_atomic_store(&hpk[((size_t)(((t + 1) & 1) * 2 + dir) * B + bg) * HD + jg], hp,
                         __ATOMIC_RELAXED, __HIP_MEMORY_SCOPE_AGENT);
      ysum[b_l * 33 + u2] = hn * w3v;
    }
    __syncthreads();   // B5 (drains vmcnt: h stores complete at coherence point)

    if (half == 0) {
      if (stid == 0)
        __hip_atomic_fetch_add(&flags[t * 16 + fl_base], 1, __ATOMIC_RELAXED,
                               __HIP_MEMORY_SCOPE_AGENT);
      if (stid < 16) {
        float s = 0.0f;
        #pragma unroll
        for (int i = 0; i < 32; ++i) s += ysum[stid * 33 + i];
        part[((size_t)t * 32 + dir * 16 + ut) * B + b0 + stid] = s;
      }
    }
  }
#undef KSTEP
#undef GEMM_MFMA
#undef GEMM_STAGE

  if (half == 0) cbuf[ci] = creg;
}

// ---------------- K5: final reduce: out[b][t] = b3 + sum_g part[t][g][b] ----------------
__global__ void k_out(const float* __restrict__ part, const float* __restrict__ b3,
                      float* __restrict__ out) {
  const int o = blockIdx.x * 256 + threadIdx.x;  // 32768
  const int b = o & 127, t = o >> 7;
  float s = b3[0];
  #pragma unroll
  for (int g = 0; g < 32; ++g) s += part[((size_t)t * 32 + g) * B + b];
  out[(size_t)b * T + t] = s;
}

}  // namespace

extern "C" void kernel_launch(void* const* d_in, const int* in_sizes, int n_in,
                              void* d_out, int out_size, void* d_ws, size_t ws_size,
                              hipStream_t stream) {
  const float* x0   = (const float*)d_in[0];
  const float* emb  = (const float*)d_in[1];
  const float* W1   = (const float*)d_in[2];
  const float* b1   = (const float*)d_in[3];
  const float* W2   = (const float*)d_in[4];
  const float* b2   = (const float*)d_in[5];
  const float* Wi_f = (const float*)d_in[6];
  const float* bi_f = (const float*)d_in[7];
  const float* Wh_f = (const float*)d_in[8];
  const float* bh_f = (const float*)d_in[9];
  const float* Wi_r = (const float*)d_in[10];
  const float* bi_r = (const float*)d_in[11];
  const float* Wh_r = (const float*)d_in[12];
  const float* bh_r = (const float*)d_in[13];
  const float* W3   = (const float*)d_in[14];
  const float* b3   = (const float*)d_in[15];
  float* out = (float*)d_out;

  // workspace layout (bytes), total ~150.6 MiB (same footprint as round 12)
  char* wsb = (char*)d_ws;
  unsigned short* x1h  = (unsigned short*)(wsb + 0);           // 33,554,432 (prologue only)
  unsigned short* x1l  = (unsigned short*)(wsb + 33554432);    // 33,554,432 (prologue only)
  float*          xgA  = (float*)(wsb + 0);                    // 33,554,432 (chunk even)
  float*          xgB  = (float*)(wsb + 33554432);             // 33,554,432 (chunk odd)
  unsigned short* x2h  = (unsigned short*)(wsb + 67108864);    // 33,554,432
  unsigned short* x2l  = (unsigned short*)(wsb + 100663296);   // 33,554,432
  unsigned short* wih  = (unsigned short*)(wsb + 134217728);   //  4,194,304
  unsigned short* wil  = (unsigned short*)(wsb + 138412032);   //  4,194,304
  unsigned short* w2h  = (unsigned short*)(wsb + 142606336);   //    524,288
  unsigned short* w2l  = (unsigned short*)(wsb + 143130624);   //    524,288
  unsigned short* wpkh = (unsigned short*)(wsb + 143654912);   //  4,194,304
  unsigned short* wpkl = (unsigned short*)(wsb + 147849216);   //  4,194,304
  unsigned int*   hpk  = (unsigned int*)(wsb + 152043520);     //  1,048,576
  float*          cbuf = (float*)(wsb + 153092096);            //    524,288
  float*          part = (float*)(wsb + 153616384);            //  4,194,304
  float*          bia  = (float*)(wsb + 157810688);            //     16,384
  int*            flg  = (int*)(wsb + 157827072);              //     16,384 (T*16 ints)

  // prep: weights
  k_prep_pack<<<dim3(1024), 256, 0, stream>>>(Wh_f, Wh_r, wpkh, wpkl);
  k_prep<<<dim3(G / 32, HD / 32), dim3(32, 8), 0, stream>>>(Wi_f, wih, wil, HD, G);
  k_prep<<<dim3(G / 32, HD / 32), dim3(32, 8), 0, stream>>>(Wi_r, wih + (size_t)G * HD, wil + (size_t)G * HD, HD, G);
  k_prep<<<dim3(HD / 32, HD / 32), dim3(32, 8), 0, stream>>>(W2, w2h, w2l, HD, HD);
  k_bias<<<dim3(16), 256, 0, stream>>>(bi_f, bh_f, bi_r, bh_r, bia);

  // flags for the whole scan (absolute-t indexing): memset once per launch
  hipMemsetAsync(flg, 0, T * 16 * sizeof(int), stream);

  // x1 = leaky(embed @ W1 + b1), bf16 hi/lo
  k_embed_gemm1<<<dim3(B * T / 64, HD / 64), 256, 0, stream>>>(x0, emb, W1, b1, x1h, x1l);

  // x2 = leaky(x1 @ W2 + b2), bf16 hi/lo (MFMA bf16x3)
  k_mm<0><<<dim3(B * T / 128, HD / 128), 512, 0, stream>>>(
      x1h, x1l, w2h, w2l, b2, x2h, x2l, nullptr, 0);

  // xg for chunk 0 (standalone); chunks 1..15 are produced in the scan's shadow
  k_mm<1><<<dim3(2 * TC * B / 128, G / 128), 512, 0, stream>>>(
      x2h, x2l, wih, wil, bia, nullptr, nullptr, xgA, 0);

  float* xgbuf[2] = {xgA, xgB};
  const float* xg_cur;
  float* xg_nxt;
  int c0 = 0, dog = 1;
  void* args[16];
  args[0]  = (void*)&xg_cur; args[1]  = (void*)&xg_nxt;
  args[2]  = (void*)&wpkh;   args[3]  = (void*)&wpkl;
  args[4]  = (void*)&hpk;    args[5]  = (void*)&cbuf;
  args[6]  = (void*)&part;   args[7]  = (void*)&W3;
  args[8]  = (void*)&flg;    args[9]  = (void*)&c0;
  args[10] = (void*)&x2h;    args[11] = (void*)&x2l;
  args[12] = (void*)&wih;    args[13] = (void*)&wil;
  args[14] = (void*)&bia;    args[15] = (void*)&dog;

  for (int c = 0; c < NCHUNK; ++c) {
    c0 = c * TC;
    dog = (c + 1 < NCHUNK) ? 1 : 0;
    xg_cur = xgbuf[c & 1];
    xg_nxt = xgbuf[(c + 1) & 1];
    hipLaunchCooperativeKernel((void*)k_scan2, dim3(256), dim3(1024), args, 0, stream);
  }

  k_out<<<dim3(B * T / 256), 256, 0, stream>>>(part, b3, out);
}

// Round 14
// 1802.294 us; speedup vs baseline: 3.0016x; 3.0016x over previous
//
#include <hip/hip_runtime.h>
#include <cstddef>

namespace {

constexpr int B  = 128;
constexpr int T  = 256;
constexpr int HD = 512;
constexpr int G  = 2048;   // 4*HD gates
constexpr int TC = 32;     // time chunk for xg buffer
constexpr int XIN = 36;    // 32 real + 4 cat
constexpr int NCHUNK = T / TC;   // 8

typedef __attribute__((ext_vector_type(8))) short short8;
typedef __attribute__((ext_vector_type(4))) short short4v;
typedef __attribute__((ext_vector_type(4))) float f32x4;

union U16B { uint4 u; short8 s; };

__device__ __forceinline__ float sigmf(float x) { return 1.0f / (1.0f + expf(-x)); }
__device__ __forceinline__ float leakyf(float x) { return x >= 0.0f ? x : 0.1f * x; }

__device__ __forceinline__ unsigned short f2bf(float v) {
  union { float f; unsigned u; } x; x.f = v;
  unsigned r = x.u + 0x7fffu + ((x.u >> 16) & 1u);
  return (unsigned short)(r >> 16);
}
__device__ __forceinline__ float bf2f(unsigned short b) {
  union { unsigned u; float f; } x; x.u = ((unsigned)b) << 16; return x.f;
}

// ---------------- prep: transpose [K][N] -> [N][K], split bf16 hi/lo ----------------
__global__ void k_prep(const float* __restrict__ src, unsigned short* __restrict__ dh,
                       unsigned short* __restrict__ dl, int K, int N) {
  __shared__ float tile[32][33];
  const int n0 = blockIdx.x * 32, k0 = blockIdx.y * 32;
  for (int i = threadIdx.y; i < 32; i += 8)
    tile[i][threadIdx.x] = src[(size_t)(k0 + i) * N + n0 + threadIdx.x];
  __syncthreads();
  for (int i = threadIdx.y; i < 32; i += 8) {
    const float v = tile[threadIdx.x][i];
    const unsigned short h = f2bf(v);
    const size_t o = (size_t)(n0 + i) * K + k0 + threadIdx.x;
    dh[o] = h;
    dl[o] = f2bf(v - bf2f(h));
  }
}

// ---------------- prep+pack Wh directly into MFMA A-fragment order ----------------
__global__ void k_prep_pack(const float* __restrict__ Whf, const float* __restrict__ Whr,
                            unsigned short* __restrict__ wpkh, unsigned short* __restrict__ wpkl) {
  const int f = blockIdx.x * 256 + threadIdx.x;   // 262144
  const int l  = f & 63;
  const int ks = (f >> 6) & 15;
  const int ct = (f >> 10) & 7;
  const int ut = (f >> 13) & 15;
  const int dir = f >> 17;
  const float* src = dir ? Whr : Whf;
  const int L = ct * 16 + (l & 15);
  const int gcol = (L >> 5) * HD + ut * 32 + (L & 31);
  const int k0 = ks * 32 + (l >> 4) * 8;
  short8 hv, lv;
  #pragma unroll
  for (int j = 0; j < 8; ++j) {
    const float v = src[(size_t)(k0 + j) * G + gcol];
    const unsigned short h = f2bf(v);
    hv[j] = (short)h;
    lv[j] = (short)f2bf(v - bf2f(h));
  }
  *(short8*)&wpkh[(size_t)f * 8] = hv;
  *(short8*)&wpkl[(size_t)f * 8] = lv;
}

__global__ void k_bias(const float* __restrict__ bif, const float* __restrict__ bhf,
                       const float* __restrict__ bir, const float* __restrict__ bhr,
                       float* __restrict__ biasI) {
  const int i = blockIdx.x * 256 + threadIdx.x;   // 4096
  const int d = i >> 11, n = i & 2047;
  biasI[i] = (d ? bir[n] : bif[n]) + (d ? bhr[n] : bhf[n]);
}

// ---------------- K1: embed-gather + GEMM (M=B*T, K=64, N=512) + leaky, out bf16 hi/lo ----------
__global__ void k_embed_gemm1(const float* __restrict__ x0, const float* __restrict__ emb,
                              const float* __restrict__ W1, const float* __restrict__ b1,
                              unsigned short* __restrict__ x1h, unsigned short* __restrict__ x1l) {
  __shared__ float As[64][65];
  __shared__ float Bs[64][68];
  const int tid = threadIdx.x;
  const int m0 = blockIdx.x * 64, n0 = blockIdx.y * 64;

  for (int i = tid; i < 64 * 64; i += 256) {
    const int m = i >> 6, k = i & 63;
    const size_t row = (size_t)(m0 + m);
    float v;
    if (k < 32) {
      v = x0[row * XIN + k];
    } else {
      const int c = (k - 32) >> 3, e = (k - 32) & 7;
      const int idx = (int)x0[row * XIN + 32 + c];
      v = emb[(size_t)(c * 100 + idx) * 8 + e];
    }
    As[m][k] = v;
  }
  for (int j = 0; j < 4; ++j) {
    const int q = tid + 256 * j;
    const int kk = q >> 4, nq = q & 15;
    *(float4*)&Bs[kk][nq * 4] = *(const float4*)&W1[(size_t)kk * HD + n0 + nq * 4];
  }
  __syncthreads();

  const int ty = tid >> 4, tx = tid & 15;
  float acc[4][4] = {};
  #pragma unroll 8
  for (int k = 0; k < 64; ++k) {
    const float a0 = As[ty * 4 + 0][k], a1 = As[ty * 4 + 1][k];
    const float a2 = As[ty * 4 + 2][k], a3 = As[ty * 4 + 3][k];
    const float4 bv = *(const float4*)&Bs[k][tx * 4];
    acc[0][0] += a0 * bv.x; acc[0][1] += a0 * bv.y; acc[0][2] += a0 * bv.z; acc[0][3] += a0 * bv.w;
    acc[1][0] += a1 * bv.x; acc[1][1] += a1 * bv.y; acc[1][2] += a1 * bv.z; acc[1][3] += a1 * bv.w;
    acc[2][0] += a2 * bv.x; acc[2][1] += a2 * bv.y; acc[2][2] += a2 * bv.z; acc[2][3] += a2 * bv.w;
    acc[3][0] += a3 * bv.x; acc[3][1] += a3 * bv.y; acc[3][2] += a3 * bv.z; acc[3][3] += a3 * bv.w;
  }
  const float4 b4 = *(const float4*)&b1[n0 + tx * 4];
  for (int i = 0; i < 4; ++i) {
    float o[4];
    o[0] = leakyf(acc[i][0] + b4.x);
    o[1] = leakyf(acc[i][1] + b4.y);
    o[2] = leakyf(acc[i][2] + b4.z);
    o[3] = leakyf(acc[i][3] + b4.w);
    short4v hv, lv;
    #pragma unroll
    for (int p = 0; p < 4; ++p) {
      const unsigned short hb = f2bf(o[p]);
      hv[p] = (short)hb;
      lv[p] = (short)f2bf(o[p] - bf2f(hb));
    }
    const size_t off = (size_t)(m0 + ty * 4 + i) * HD + n0 + tx * 4;
    *(short4v*)&x1h[off] = hv;
    *(short4v*)&x1l[off] = lv;
  }
}

// ---------------- K2/K3: bf16x3 MFMA GEMM, tile 128x128, BK=32 ----------------
template <int MODE>
__global__ __launch_bounds__(512) void k_mm(
    const unsigned short* __restrict__ Ah, const unsigned short* __restrict__ Al,
    const unsigned short* __restrict__ Bh, const unsigned short* __restrict__ Bl,
    const float* __restrict__ bias,
    unsigned short* __restrict__ oh, unsigned short* __restrict__ ol,
    float* __restrict__ of, int c0) {
  __shared__ unsigned short As_h[128 * 40], As_l[128 * 40];
  __shared__ unsigned short Bs_h[128 * 40], Bs_l[128 * 40];
  const int tid = threadIdx.x;
  const int m0 = blockIdx.x * 128, n0 = blockIdx.y * 128;
  const int dir = MODE ? (m0 >> 12) : 0;
  const unsigned short* Bhd = Bh + (size_t)dir * G * HD;
  const unsigned short* Bld = Bl + (size_t)dir * G * HD;

  const int si = tid >> 2, sseg = tid & 3;
  int arow;
  if (MODE) {
    const int r = m0 + si;
    const int tc = (r >> 7) & 31, bb = r & 127;
    const int tg = dir ? (T - 1 - (c0 + tc)) : (c0 + tc);
    arow = bb * T + tg;
  } else {
    arow = m0 + si;
  }
  const int brow = n0 + si;

  const int lane = tid & 63;
  const int c16 = lane & 15, q = lane >> 4;
  const int w = tid >> 6;
  const int mg = w & 3, ng = w >> 2;

  f32x4 acc[2][4] = {};

  for (int k0 = 0; k0 < HD; k0 += 32) {
    __syncthreads();
    *(short8*)&As_h[si * 40 + sseg * 8] = *(const short8*)&Ah[(size_t)arow * HD + k0 + sseg * 8];
    *(short8*)&As_l[si * 40 + sseg * 8] = *(const short8*)&Al[(size_t)arow * HD + k0 + sseg * 8];
    *(short8*)&Bs_h[si * 40 + sseg * 8] = *(const short8*)&Bhd[(size_t)brow * HD + k0 + sseg * 8];
    *(short8*)&Bs_l[si * 40 + sseg * 8] = *(const short8*)&Bld[(size_t)brow * HD + k0 + sseg * 8];
    __syncthreads();

    short8 ah[2], al[2], bh[4], bl[4];
    #pragma unroll
    for (int a = 0; a < 2; ++a) {
      const int rr = (2 * mg + a) * 16 + c16;
      ah[a] = *(const short8*)&As_h[rr * 40 + q * 8];
      al[a] = *(const short8*)&As_l[rr * 40 + q * 8];
    }
    #pragma unroll
    for (int j = 0; j < 4; ++j) {
      const int rr = (4 * ng + j) * 16 + c16;
      bh[j] = *(const short8*)&Bs_h[rr * 40 + q * 8];
      bl[j] = *(const short8*)&Bs_l[rr * 40 + q * 8];
    }
    #pragma unroll
    for (int a = 0; a < 2; ++a)
      #pragma unroll
      for (int j = 0; j < 4; ++j) {
        acc[a][j] = __builtin_amdgcn_mfma_f32_16x16x32_bf16(ah[a], bh[j], acc[a][j], 0, 0, 0);
        acc[a][j] = __builtin_amdgcn_mfma_f32_16x16x32_bf16(ah[a], bl[j], acc[a][j], 0, 0, 0);
        acc[a][j] = __builtin_amdgcn_mfma_f32_16x16x32_bf16(al[a], bh[j], acc[a][j], 0, 0, 0);
      }
  }

  #pragma unroll
  for (int a = 0; a < 2; ++a) {
    #pragma unroll
    for (int j = 0; j < 4; ++j) {
      const int nn = n0 + (4 * ng + j) * 16 + c16;
      const float bv = MODE ? bias[dir * G + nn] : bias[nn];
      #pragma unroll
      for (int r = 0; r < 4; ++r) {
        const int mm = m0 + (2 * mg + a) * 16 + 4 * q + r;
        float v = acc[a][j][r] + bv;
        if (MODE) {
          of[(size_t)mm * G + nn] = v;
        } else {
          v = leakyf(v);
          const unsigned short hb = f2bf(v);
          oh[(size_t)mm * HD + nn] = hb;
          ol[(size_t)mm * HD + nn] = f2bf(v - bf2f(hb));
        }
      }
    }
  }
}

// ---------------- K4: persistent per-chunk scan (round-12 champion, verbatim) ----------------
// 256 blocks x 512 thr (cooperative). IDENTITY block decode (bid%8 = bt: each h-exchange
// group sits on one XCD — r10's weight-swizzle regressed 2.4x, do not swizzle).
// Staging: iter = batch row, lane(tid) = k -> fully coalesced 2KB coherent loads, stride-1
// LDS writes; hi/lo unpack via perm INSIDE KSTEP (r11's perm-at-staging regressed 33%).
// Flags indexed by ABSOLUTE step t (16 KB buffer, memset once per launch).
// Overlap attempts r7/r8 (coop>256 blocks), r9 (same-thread interleave), r13 (wave
// specialization, VGPR-capped spills) ALL regressed — this serial structure is the optimum
// reachable under the harness constraints (no hipEvent -> no multi-stream under capture).
__global__ __launch_bounds__(512, 2) void k_scan(
    const float* __restrict__ xg, const unsigned short* __restrict__ wpkh,
    const unsigned short* __restrict__ wpkl, unsigned int* __restrict__ hpk,
    float* __restrict__ cbuf, float* __restrict__ part,
    const float* __restrict__ W3, int* __restrict__ flags, int c0) {
  __shared__ unsigned int hst[16 * 516];   // staged packed h(t-1): [b][k]
  __shared__ float gl[128 * 17];           // [L = g*32+ul][b]
  __shared__ float ysum[16 * 33];

  const int tid = threadIdx.x;
  const int bid = blockIdx.x;
  const int dir = bid >> 7;
  const int ut  = (bid >> 3) & 15;
  const int bt  = bid & 7;
  const int u0 = ut * 32, b0 = bt * 16;
  const int w = tid >> 6, lane = tid & 63;
  const int r16 = lane & 15, q = lane >> 4;

  // ---- weight fragment loads (compiler streams from cache each step; 92 VGPR kernel) ----
  const unsigned short* wp = wpkh + ((size_t)(((dir * 16 + ut) * 8 + w) * 16) << 9) + lane * 8;
  const unsigned short* wq = wpkl + ((size_t)(((dir * 16 + ut) * 8 + w) * 16) << 9) + lane * 8;
#define LDW(K) const short8 wh##K = *(const short8*)(wp + (K) * 512); \
               const short8 wl##K = *(const short8*)(wq + (K) * 512);
  LDW(0) LDW(1) LDW(2) LDW(3) LDW(4) LDW(5) LDW(6) LDW(7)
  LDW(8) LDW(9) LDW(10) LDW(11) LDW(12) LDW(13) LDW(14) LDW(15)
#undef LDW

  // ---- per-thread recurrent state ----
  const int b_l = tid >> 5, u2 = tid & 31;
  const int bg = b0 + b_l, jg = u0 + u2;
  const size_t ci = ((size_t)dir * B + bg) * HD + jg;
  float creg = (c0 == 0) ? 0.0f : cbuf[ci];
  const float w3v = W3[dir * HD + jg];
  const int fl_base = dir * 8 + bt;
  const int hb = r16 * 516 + q * 8;

#define KSTEP(K) { \
    const uint4 aa = *(const uint4*)&hst[hb + (K) * 32]; \
    const uint4 bb = *(const uint4*)&hst[hb + (K) * 32 + 4]; \
    U16B hiu, lou; \
    hiu.u.x = __builtin_amdgcn_perm(aa.y, aa.x, 0x07060302u); \
    hiu.u.y = __builtin_amdgcn_perm(aa.w, aa.z, 0x07060302u); \
    hiu.u.z = __builtin_amdgcn_perm(bb.y, bb.x, 0x07060302u); \
    hiu.u.w = __builtin_amdgcn_perm(bb.w, bb.z, 0x07060302u); \
    lou.u.x = __builtin_amdgcn_perm(aa.y, aa.x, 0x05040100u); \
    lou.u.y = __builtin_amdgcn_perm(aa.w, aa.z, 0x05040100u); \
    lou.u.z = __builtin_amdgcn_perm(bb.y, bb.x, 0x05040100u); \
    lou.u.w = __builtin_amdgcn_perm(bb.w, bb.z, 0x05040100u); \
    acc = __builtin_amdgcn_mfma_f32_16x16x32_bf16(wh##K, hiu.s, acc, 0, 0, 0); \
    acc = __builtin_amdgcn_mfma_f32_16x16x32_bf16(wh##K, lou.s, acc, 0, 0, 0); \
    acc = __builtin_amdgcn_mfma_f32_16x16x32_bf16(wl##K, hiu.s, acc, 0, 0, 0); }

  for (int tc = 0; tc < TC; ++tc) {
    const int t = c0 + tc;

    // ---- prefetch this step's xg gate values (independent of h) ----
    const float* xr = xg + (((size_t)dir * TC + tc) * B + bg) * G;
    const float xgf = xr[jg];
    const float xgi = xr[HD + jg];
    const float xga = xr[2 * HD + jg];
    const float xgo = xr[3 * HD + jg];

    f32x4 acc = {0.0f, 0.0f, 0.0f, 0.0f};
    if (t > 0) {
      if (tc > 0) {
        if (tid == 0) {
          while (__hip_atomic_load(&flags[(t - 1) * 16 + fl_base], __ATOMIC_RELAXED,
                                   __HIP_MEMORY_SCOPE_AGENT) < 16)
            __builtin_amdgcn_s_sleep(1);
        }
        __syncthreads();
      }
      // stage h(t-1) (slot t&1): iter = local batch row, lane = k (coalesced 2KB/instr)
      {
        const unsigned int* hsrc = hpk + ((size_t)((t & 1) * 2 + dir) * B + b0) * HD;
        unsigned int hv[16];
        #pragma unroll
        for (int i = 0; i < 16; ++i)
          hv[i] = __hip_atomic_load(&hsrc[i * HD + tid], __ATOMIC_RELAXED,
                                    __HIP_MEMORY_SCOPE_AGENT);
        #pragma unroll
        for (int i = 0; i < 16; ++i)
          hst[i * 516 + tid] = hv[i];
      }
      __syncthreads();
      KSTEP(0) KSTEP(1) KSTEP(2) KSTEP(3) KSTEP(4) KSTEP(5) KSTEP(6) KSTEP(7)
      KSTEP(8) KSTEP(9) KSTEP(10) KSTEP(11) KSTEP(12) KSTEP(13) KSTEP(14) KSTEP(15)
      __syncthreads();   // hst reads done before next overwrite
    }

    // scatter gates: L = w*16 + q*4 + r, batch = r16
    gl[(w * 16 + q * 4 + 0) * 17 + r16] = acc[0];
    gl[(w * 16 + q * 4 + 1) * 17 + r16] = acc[1];
    gl[(w * 16 + q * 4 + 2) * 17 + r16] = acc[2];
    gl[(w * 16 + q * 4 + 3) * 17 + r16] = acc[3];
    __syncthreads();

    // epilogue: one (b_l, u2) per thread
    {
      const float gf = gl[(u2) * 17 + b_l]      + xgf;
      const float gi = gl[(32 + u2) * 17 + b_l] + xgi;
      const float ga = gl[(64 + u2) * 17 + b_l] + xga;
      const float go = gl[(96 + u2) * 17 + b_l] + xgo;
      const float cn = sigmf(gf) * creg + sigmf(gi) * tanhf(ga);
      const float hn = sigmf(go) * tanhf(cn);
      creg = cn;
      const unsigned short hh = f2bf(hn);
      const unsigned int hp = ((unsigned)hh << 16) | (unsigned)f2bf(hn - bf2f(hh));
      __hip_atomic_store(&hpk[((size_t)(((t + 1) & 1) * 2 + dir) * B + bg) * HD + jg], hp,
                         __ATOMIC_RELAXED, __HIP_MEMORY_SCOPE_AGENT);
      ysum[b_l * 33 + u2] = hn * w3v;
    }
    __syncthreads();   // drains vmcnt: h stores complete at coherence point

    if (tid == 0)
      __hip_atomic_fetch_add(&flags[t * 16 + fl_base], 1, __ATOMIC_RELAXED,
                             __HIP_MEMORY_SCOPE_AGENT);
    if (tid < 16) {
      float s = 0.0f;
      #pragma unroll
      for (int i = 0; i < 32; ++i) s += ysum[tid * 33 + i];
      part[((size_t)t * 32 + dir * 16 + ut) * B + b0 + tid] = s;
    }
  }
#undef KSTEP

  cbuf[ci] = creg;
}

// ---------------- K5: final reduce: out[b][t] = b3 + sum_g part[t][g][b] ----------------
__global__ void k_out(const float* __restrict__ part, const float* __restrict__ b3,
                      float* __restrict__ out) {
  const int o = blockIdx.x * 256 + threadIdx.x;  // 32768
  const int b = o & 127, t = o >> 7;
  float s = b3[0];
  #pragma unroll
  for (int g = 0; g < 32; ++g) s += part[((size_t)t * 32 + g) * B + b];
  out[(size_t)b * T + t] = s;
}

}  // namespace

extern "C" void kernel_launch(void* const* d_in, const int* in_sizes, int n_in,
                              void* d_out, int out_size, void* d_ws, size_t ws_size,
                              hipStream_t stream) {
  const float* x0   = (const float*)d_in[0];
  const float* emb  = (const float*)d_in[1];
  const float* W1   = (const float*)d_in[2];
  const float* b1   = (const float*)d_in[3];
  const float* W2   = (const float*)d_in[4];
  const float* b2   = (const float*)d_in[5];
  const float* Wi_f = (const float*)d_in[6];
  const float* bi_f = (const float*)d_in[7];
  const float* Wh_f = (const float*)d_in[8];
  const float* bh_f = (const float*)d_in[9];
  const float* Wi_r = (const float*)d_in[10];
  const float* bi_r = (const float*)d_in[11];
  const float* Wh_r = (const float*)d_in[12];
  const float* bh_r = (const float*)d_in[13];
  const float* W3   = (const float*)d_in[14];
  const float* b3   = (const float*)d_in[15];
  float* out = (float*)d_out;

  // workspace layout (bytes), total ~150.6 MiB
  char* wsb = (char*)d_ws;
  unsigned short* x1h  = (unsigned short*)(wsb + 0);           // 33,554,432 (then xgf)
  unsigned short* x1l  = (unsigned short*)(wsb + 33554432);    // 33,554,432
  float*          xgf  = (float*)(wsb + 0);                    // 67,108,864 (after gemm2)
  unsigned short* x2h  = (unsigned short*)(wsb + 67108864);    // 33,554,432
  unsigned short* x2l  = (unsigned short*)(wsb + 100663296);   // 33,554,432
  unsigned short* wih  = (unsigned short*)(wsb + 134217728);   //  4,194,304
  unsigned short* wil  = (unsigned short*)(wsb + 138412032);   //  4,194,304
  unsigned short* w2h  = (unsigned short*)(wsb + 142606336);   //    524,288
  unsigned short* w2l  = (unsigned short*)(wsb + 143130624);   //    524,288
  unsigned short* wpkh = (unsigned short*)(wsb + 143654912);   //  4,194,304
  unsigned short* wpkl = (unsigned short*)(wsb + 147849216);   //  4,194,304
  unsigned int*   hpk  = (unsigned int*)(wsb + 152043520);     //  1,048,576
  float*          cbuf = (float*)(wsb + 153092096);            //    524,288
  float*          part = (float*)(wsb + 153616384);            //  4,194,304
  float*          bia  = (float*)(wsb + 157810688);            //     16,384
  int*            flg  = (int*)(wsb + 157827072);              //     16,384 (T*16 ints)

  // prep: weights
  k_prep_pack<<<dim3(1024), 256, 0, stream>>>(Wh_f, Wh_r, wpkh, wpkl);
  k_prep<<<dim3(G / 32, HD / 32), dim3(32, 8), 0, stream>>>(Wi_f, wih, wil, HD, G);
  k_prep<<<dim3(G / 32, HD / 32), dim3(32, 8), 0, stream>>>(Wi_r, wih + (size_t)G * HD, wil + (size_t)G * HD, HD, G);
  k_prep<<<dim3(HD / 32, HD / 32), dim3(32, 8), 0, stream>>>(W2, w2h, w2l, HD, HD);
  k_bias<<<dim3(16), 256, 0, stream>>>(bi_f, bh_f, bi_r, bh_r, bia);

  // flags for the whole scan: each word written exactly once; memset once per launch
  hipMemsetAsync(flg, 0, T * 16 * sizeof(int), stream);

  // x1 = leaky(embed @ W1 + b1), bf16 hi/lo
  k_embed_gemm1<<<dim3(B * T / 64, HD / 64), 256, 0, stream>>>(x0, emb, W1, b1, x1h, x1l);

  // x2 = leaky(x1 @ W2 + b2), bf16 hi/lo (MFMA bf16x3)
  k_mm<0><<<dim3(B * T / 128, HD / 128), 512, 0, stream>>>(
      x1h, x1l, w2h, w2l, b2, x2h, x2l, nullptr, 0);

  void* args[9];
  int c0 = 0;
  args[0] = (void*)&xgf;  args[1] = (void*)&wpkh; args[2] = (void*)&wpkl;
  args[3] = (void*)&hpk;  args[4] = (void*)&cbuf; args[5] = (void*)&part;
  args[6] = (void*)&W3;   args[7] = (void*)&flg;  args[8] = (void*)&c0;

  for (int c = 0; c < NCHUNK; ++c) {
    c0 = c * TC;
    k_mm<1><<<dim3(2 * TC * B / 128, G / 128), 512, 0, stream>>>(
        x2h, x2l, wih, wil, bia, nullptr, nullptr, xgf, c0);
    hipLaunchCooperativeKernel((void*)k_scan, dim3(256), dim3(512), args, 0, stream);
  }

  k_out<<<dim3(B * T / 256), 256, 0, stream>>>(part, b3, out);
}